// Round 1
// baseline (402.211 us; speedup 1.0000x reference)
//
#include <hip/hip_runtime.h>
#include <hip/hip_bf16.h>

typedef __attribute__((ext_vector_type(8))) short short8;
typedef __attribute__((ext_vector_type(4))) float f32x4;

#define NCELL 8192
#define NGENE 10000
#define KD 32
#define ZD 100
#define HD 256
#define GD 100   // z_dim of output (gen_Z rows)

__device__ __forceinline__ float gelu_exact(float x) {
    return 0.5f * x * (1.0f + erff(x * 0.70710678118654752f));
}

// ---------------- Kernel 1: key_t[32][8192] = (gelu(Z^T Wz1 + bz1) Wz2 + bz2)^T
__global__ void key_kernel(const float* __restrict__ rawZ,
                           const float* __restrict__ Wz1, const float* __restrict__ bz1,
                           const float* __restrict__ Wz2, const float* __restrict__ bz2,
                           float* __restrict__ key_t) {
    __shared__ float z[8][ZD];
    __shared__ float h[8][HD];
    const int t = threadIdx.x;
    const int c0 = blockIdx.x * 8;
    for (int idx = t; idx < 8 * ZD; idx += 256) {
        int cell = idx / ZD, i = idx - cell * ZD;
        z[cell][i] = rawZ[i * NCELL + c0 + cell];
    }
    __syncthreads();
    float a[8];
#pragma unroll
    for (int cl = 0; cl < 8; ++cl) a[cl] = bz1[t];
    for (int i = 0; i < ZD; ++i) {
        float wv = Wz1[i * HD + t];
#pragma unroll
        for (int cl = 0; cl < 8; ++cl) a[cl] += z[cl][i] * wv;
    }
#pragma unroll
    for (int cl = 0; cl < 8; ++cl) h[cl][t] = gelu_exact(a[cl]);
    __syncthreads();
    const int cell = t >> 5, kk = t & 31;
    float b = bz2[kk];
    for (int j = 0; j < HD; ++j) b += h[cell][j] * Wz2[j * KD + kk];
    key_t[kk * NCELL + c0 + cell] = b;
}

// ---------------- Kernel 2: qs[10000][32], pre-scaled by 1/sqrt(32)
__global__ void query_kernel(const float* __restrict__ Grep,
                             const float* __restrict__ Wg1, const float* __restrict__ bg1,
                             const float* __restrict__ Wg2, const float* __restrict__ bg2,
                             float* __restrict__ qs) {
    __shared__ float gr[8][GD];
    __shared__ float hq[8][KD];
    const int t = threadIdx.x;
    const int g0 = blockIdx.x * 8;
    for (int idx = t; idx < 8 * GD; idx += 256) {
        int ge = idx / GD, i = idx - ge * GD;
        gr[ge][i] = Grep[(g0 + ge) * GD + i];
    }
    __syncthreads();
    const int ge = t >> 5, kk = t & 31;
    float a = bg1[kk];
    for (int i = 0; i < GD; ++i) a += gr[ge][i] * Wg1[i * KD + kk];
    hq[ge][kk] = gelu_exact(a);
    __syncthreads();
    float b = bg2[kk];
#pragma unroll
    for (int j = 0; j < KD; ++j) b += hq[ge][j] * Wg2[j * KD + kk];
    qs[(g0 + ge) * KD + kk] = b * 0.17677669529663687f; // 1/sqrt(32)
}

// ---------------- Kernel 3: genZB — gen_Z repacked to bf16 in MFMA B-fragment-linear order.
// Fragment κ: lane l = n + 16*b (n = d offset, b = k-block), elem j, k = 8*b + j.
// genZB[((cb*8 + db)*64 + l)*8 + j] = bf16(gen_Z[db*16 + (l&15)][cb*32 + 8*((l>>4)&3) + j])
__global__ void vprep_kernel(const float* __restrict__ genZ, ushort* __restrict__ genZB) {
    int o = blockIdx.x * 256 + threadIdx.x; // 1,048,576 total
    int j = o & 7;
    int l = (o >> 3) & 63;
    int db = (o >> 9) & 7;
    int cb = o >> 12;
    int c = cb * 32 + ((l >> 4) & 3) * 8 + j;
    int d = db * 16 + (l & 15);
    float v = (d < GD) ? genZ[d * NCELL + c] : 0.0f;
    __hip_bfloat16 bv = __float2bfloat16(v);
    genZB[o] = *reinterpret_cast<ushort*>(&bv);
}

// ---------------- Kernel 4: fused flash attention (f32 scores, online softmax, bf16 MFMA PV)
// 512 threads = 8 waves; 16 genes/block (2 per wave for S); wave w owns output d-tile [16w,16w+16)
__launch_bounds__(512)
__global__ void fused_kernel(const float* __restrict__ gumbel,
                             const float* __restrict__ key_t,
                             const float* __restrict__ qs,
                             const ushort* __restrict__ genZB,
                             float* __restrict__ out) {
    __shared__ __align__(16) ushort p_lds[2 * 64 * 8]; // 2 k-blocks x 64 lanes x 8 elems (bf16)
    __shared__ __align__(16) float alpha_lds[16];
    __shared__ __align__(16) float linv_lds[16];
    const int t = threadIdx.x;
    const int lane = t & 63;
    const int w = t >> 6;
    const int g0 = blockIdx.x * 16;
    const int gA = g0 + 2 * w, gB = gA + 1;

    // q rows -> SGPRs (wave-uniform)
    float qA[KD], qB[KD];
#pragma unroll
    for (int k = 0; k < KD; ++k) {
        qA[k] = __uint_as_float(__builtin_amdgcn_readfirstlane(__float_as_uint(qs[gA * KD + k])));
        qB[k] = __uint_as_float(__builtin_amdgcn_readfirstlane(__float_as_uint(qs[gB * KD + k])));
    }

    float mA = -1e30f, mB = -1e30f, lA = 0.f, lB = 0.f;
    f32x4 acc = {0.f, 0.f, 0.f, 0.f};

    // P staging address (A-fragment-linear, same κ as genZB): row = local gene, k = lane&31
    const int cb = lane >> 5;
    const int kk = lane & 31;
    const int jj = kk & 7, bsub = kk >> 3;
    const int rowA_l = 2 * w, rowB_l = 2 * w + 1;
    const int pdstA = (cb * 64 + rowA_l + 16 * bsub) * 8 + jj;
    const int pdstB = (cb * 64 + rowB_l + 16 * bsub) * 8 + jj;

    for (int it = 0; it < 128; ++it) {
        const int c = it * 64 + lane;
        float sA = gumbel[(size_t)gA * NCELL + c];
        float sB = gumbel[(size_t)gB * NCELL + c];
#pragma unroll
        for (int k = 0; k < KD; ++k) {
            float kv = key_t[k * NCELL + c];
            sA += qA[k] * kv;
            sB += qB[k] * kv;
        }
        // wave-wide tile max
        float tA = sA, tB = sB;
#pragma unroll
        for (int off = 32; off > 0; off >>= 1) {
            tA = fmaxf(tA, __shfl_xor(tA, off, 64));
            tB = fmaxf(tB, __shfl_xor(tB, off, 64));
        }
        float mAn = fmaxf(mA, tA), mBn = fmaxf(mB, tB);
        float aA = __expf(mA - mAn), aB = __expf(mB - mBn);
        float pA = __expf(sA - mAn), pB = __expf(sB - mBn);
        lA = lA * aA + pA;
        lB = lB * aB + pB;
        mA = mAn; mB = mBn;
        __hip_bfloat16 hA = __float2bfloat16(pA), hB = __float2bfloat16(pB);
        p_lds[pdstA] = *reinterpret_cast<ushort*>(&hA);
        p_lds[pdstB] = *reinterpret_cast<ushort*>(&hB);
        if (lane == 0) { alpha_lds[rowA_l] = aA; alpha_lds[rowB_l] = aB; }
        __syncthreads();
        // ---- PV: O[16 genes][d-tile w] += P(16x64) @ V(64x16)
        const f32x4 al = *reinterpret_cast<const f32x4*>(&alpha_lds[(lane >> 4) * 4]);
        acc.x *= al.x; acc.y *= al.y; acc.z *= al.z; acc.w *= al.w;
        const short8* pf = reinterpret_cast<const short8*>(p_lds);
        short8 a0 = pf[lane];
        short8 a1 = pf[64 + lane];
        const short8* bfp = reinterpret_cast<const short8*>(genZB);
        short8 b0 = bfp[((it * 2 + 0) * 8 + w) * 64 + lane];
        short8 b1 = bfp[((it * 2 + 1) * 8 + w) * 64 + lane];
        acc = __builtin_amdgcn_mfma_f32_16x16x32_bf16(a0, b0, acc, 0, 0, 0);
        acc = __builtin_amdgcn_mfma_f32_16x16x32_bf16(a1, b1, acc, 0, 0, 0);
        __syncthreads();
    }
    // final L per gene (per-lane partials share the wave-uniform running max)
    float LA = lA, LB = lB;
#pragma unroll
    for (int off = 32; off > 0; off >>= 1) {
        LA += __shfl_xor(LA, off, 64);
        LB += __shfl_xor(LB, off, 64);
    }
    if (lane == 0) { linv_lds[rowA_l] = 1.0f / LA; linv_lds[rowB_l] = 1.0f / LB; }
    __syncthreads();
    const int d = 16 * w + (lane & 15);
    if (d < GD) {
#pragma unroll
        for (int r = 0; r < 4; ++r) {
            int gl = (lane >> 4) * 4 + r; // C/D: row = (lane>>4)*4 + reg (HW-verified)
            out[(size_t)d * NGENE + g0 + gl] = acc[r] * linv_lds[gl];
        }
    }
}

extern "C" void kernel_launch(void* const* d_in, const int* in_sizes, int n_in,
                              void* d_out, int out_size, void* d_ws, size_t ws_size,
                              hipStream_t stream) {
    const float* rawZ  = (const float*)d_in[0];
    const float* genZ  = (const float*)d_in[1];
    const float* Grep  = (const float*)d_in[2];
    const float* gumb  = (const float*)d_in[3];
    const float* Wz1   = (const float*)d_in[4];
    const float* bz1   = (const float*)d_in[5];
    const float* Wz2   = (const float*)d_in[6];
    const float* bz2   = (const float*)d_in[7];
    const float* Wg1   = (const float*)d_in[8];
    const float* bg1   = (const float*)d_in[9];
    const float* Wg2   = (const float*)d_in[10];
    const float* bg2   = (const float*)d_in[11];
    float* out = (float*)d_out;

    // ws layout: key_t (1 MB) | qs (1.28 MB) | genZB (2 MB)  -> total ~4.3 MB
    float*  key_t = (float*)d_ws;
    float*  qs    = (float*)((char*)d_ws + (1 << 20));
    ushort* genZB = (ushort*)((char*)d_ws + (1 << 20) + 1280000);

    hipLaunchKernelGGL(key_kernel,   dim3(NCELL / 8), dim3(256), 0, stream,
                       rawZ, Wz1, bz1, Wz2, bz2, key_t);
    hipLaunchKernelGGL(query_kernel, dim3(NGENE / 8), dim3(256), 0, stream,
                       Grep, Wg1, bg1, Wg2, bg2, qs);
    hipLaunchKernelGGL(vprep_kernel, dim3((256 * 8 * 64 * 8) / 256), dim3(256), 0, stream,
                       genZ, genZB);
    hipLaunchKernelGGL(fused_kernel, dim3(NGENE / 16), dim3(512), 0, stream,
                       gumb, key_t, qs, genZB, out);
}